// Round 10
// baseline (453.467 us; speedup 1.0000x reference)
//
#include <hip/hip_runtime.h>

#define NB 2
#define NC 256
#define NHH 40
#define NSP 64000      // 40*40*40
#define PL 1600        // 40*40
#define SCALE 0.17677669529663687f  // 1/sqrt(32)

typedef unsigned short u16;
typedef unsigned int   u32;

typedef __attribute__((ext_vector_type(8))) short bf16x8;  // 8 bf16 = 4 VGPRs
typedef __attribute__((ext_vector_type(4))) float f32x4;

__device__ __forceinline__ float bf2f(u16 u) {
    union { u32 i; float f; } c; c.i = ((u32)u) << 16; return c.f;
}
__device__ __forceinline__ u16 f2bf(float f) {
    union { u32 i; float f; } c; c.f = f; u32 x = c.i;
    return (u16)((x + 0x7fffu + ((x >> 16) & 1u)) >> 16);
}
__device__ __forceinline__ u32 pack2(float a, float b) {
    return (u32)f2bf(a) | ((u32)f2bf(b) << 16);
}
__device__ __forceinline__ f32x4 zero4() {
    f32x4 z; z[0] = 0.f; z[1] = 0.f; z[2] = 0.f; z[3] = 0.f; return z;
}
__device__ __forceinline__ bf16x8 zero8() {
    bf16x8 z;
#pragma unroll
    for (int e = 0; e < 8; ++e) z[e] = 0;
    return z;
}

// ---------------------------------------------------------------------------
// Weight pre-conversion fp32 -> bf16 ([768][256] concat for qkv; [256][256] wp)
// ---------------------------------------------------------------------------
__global__ __launch_bounds__(256) void wcvt3(
    const float* __restrict__ wq, const float* __restrict__ wk,
    const float* __restrict__ wv, u16* __restrict__ dst)
{
    const int g   = blockIdx.x * 256 + threadIdx.x;
    const int mat = g >> 14;
    const int off = (g & 16383) << 2;
    const float* s = (mat == 0) ? wq : ((mat == 1) ? wk : wv);
    const float4 f = *(const float4*)(s + off);
    ushort4 p;
    p.x = f2bf(f.x); p.y = f2bf(f.y); p.z = f2bf(f.z); p.w = f2bf(f.w);
    *(ushort4*)(dst + (mat << 16) + off) = p;
}

__global__ __launch_bounds__(256) void wcvt1(
    const float* __restrict__ w, u16* __restrict__ dst)
{
    const int g   = blockIdx.x * 256 + threadIdx.x;
    const int off = g << 2;
    const float4 f = *(const float4*)(w + off);
    ushort4 p;
    p.x = f2bf(f.x); p.y = f2bf(f.y); p.z = f2bf(f.z); p.w = f2bf(f.w);
    *(ushort4*)(dst + off) = p;
}

// ---------------------------------------------------------------------------
// QKV v3: low-register weight-stationary GEMM targeting 16 waves/CU.
// Block: 256 thr (4 waves), M=128 o-rows (32/wave, af[8][2]=64 VGPR),
// N=4x64 tiles, K=256. m2 = blockIdx.x % 6 INNERMOST (6 blocks sharing an
// X-tile dispatch adjacently -> L3 serves re-reads). Single-buffer LDS
// (33.8 KB -> 4 blocks/CU); cross-block overlap hides staging latency.
// ---------------------------------------------------------------------------
__global__ __launch_bounds__(256, 4) void qkv3(
    const float* __restrict__ x, const u16* __restrict__ wb,  // [768][256] bf16
    const float* __restrict__ bq, const float* __restrict__ bk,
    const float* __restrict__ bv,
    u16* __restrict__ q, u16* __restrict__ k, u16* __restrict__ v)
{
    const int b    = blockIdx.z;
    const int m2   = blockIdx.x % 6;      // innermost: o-rows [128*m2, +128)
    const int gx   = blockIdx.x / 6;      // 0..249
    const int t    = threadIdx.x;
    const int lane = t & 63;
    const int wid  = t >> 6;
    const int row  = lane & 15;
    const int kg   = (lane >> 4) << 3;    // 0,8,16,24
    const int g4   = (lane >> 4) << 2;    // 0,4,8,12

    __shared__ u16 xs[64][264];           // [n][c] transposed X tile

    const float* xb = x + (size_t)b * NC * NSP;

    // ---- W panel once: 32 rows/wave, af[kc][i] (64 VGPRs)
    const int orow = m2 * 128 + wid * 32; // global row in [768][256]
    bf16x8 af[8][2];
#pragma unroll
    for (int kc = 0; kc < 8; ++kc)
#pragma unroll
        for (int i = 0; i < 2; ++i)
            af[kc][i] = *(const bf16x8*)(wb + (size_t)(orow + 16 * i + row) * NC
                                            + kc * 32 + kg);

    const int mat   = m2 >> 1;                       // 0,0,1,1,2,2
    const int obas0 = (m2 & 1) * 128 + wid * 32;     // local o base (0..224)
    u16* op = ((mat == 0) ? q : ((mat == 1) ? k : v)) + (size_t)b * NC * NSP;
    const float* bm = (mat == 0) ? bq : ((mat == 1) ? bk : bv);

    for (int tt = 0; tt < 4; ++tt) {
        const int n0 = (gx * 4 + tt) * 64;

        __syncthreads();   // previous tile's readers done
        // ---- stage X: transpose to [n][c], fp32 -> bf16, rotated writes ----
        {
            const int p   = t >> 4;          // 0..15 c-pair group
            const int nn  = (t & 15) << 2;   // rows nn..nn+3
            const int rot = (t >> 1) & 3;
#pragma unroll
            for (int it = 0; it < 8; ++it) {
                const int c = (it * 16 + p) * 2;
                const float4 fa = *(const float4*)(xb + (size_t)c * NSP + n0 + nn);
                const float4 fb = *(const float4*)(xb + (size_t)(c + 1) * NSP + n0 + nn);
                u32 pk[4] = { pack2(fa.x, fb.x), pack2(fa.y, fb.y),
                              pack2(fa.z, fb.z), pack2(fa.w, fb.w) };
#pragma unroll
                for (int kk = 0; kk < 4; ++kk) {
                    const int k2 = (kk + rot) & 3;
                    *(u32*)&xs[nn + k2][c] = pk[k2];
                }
            }
        }
        __syncthreads();

        f32x4 acc[2][4];
#pragma unroll
        for (int i = 0; i < 2; ++i)
#pragma unroll
            for (int j = 0; j < 4; ++j) acc[i][j] = zero4();

#pragma unroll
        for (int kc = 0; kc < 8; ++kc) {
            bf16x8 bfr[4];
#pragma unroll
            for (int j = 0; j < 4; ++j)
                bfr[j] = *(const bf16x8*)&xs[16 * j + row][kc * 32 + kg];
#pragma unroll
            for (int i = 0; i < 2; ++i)
#pragma unroll
                for (int j = 0; j < 4; ++j)
                    acc[i][j] = __builtin_amdgcn_mfma_f32_16x16x32_bf16(
                        af[kc][i], bfr[j], acc[i][j], 0, 0, 0);
        }

        // epilogue: C-layout col=lane&15 (n), row=g4+r (o)
#pragma unroll
        for (int i = 0; i < 2; ++i) {
#pragma unroll
            for (int r = 0; r < 4; ++r) {
                const int o = obas0 + 16 * i + g4 + r;
                const float bb = bm[o];
#pragma unroll
                for (int j = 0; j < 4; ++j) {
                    const int n = n0 + 16 * j + row;
                    op[(size_t)o * NSP + n] = f2bf(acc[i][j][r] + bb);
                }
            }
        }
    }
}

// ---------------------------------------------------------------------------
// Attention via MFMA (unchanged): 1 wave per (b,ch,h) slice.
// ---------------------------------------------------------------------------
__global__ __launch_bounds__(64, 4) void attn_mfma(
    const u16* __restrict__ q, const u16* __restrict__ k,
    const u16* __restrict__ v, u16* __restrict__ a)
{
    const int s = blockIdx.x;
    const size_t base = (size_t)s * PL;
    const int l = threadIdx.x & 63;
    const int g = l >> 4;
    const int c = l & 15;

    __shared__ u16 vs[48][56];
    __shared__ u16 ps[48][56];

#pragma unroll
    for (int it = 0; it < 3; ++it) {
        const int t = l + it * 64;
        *(u32*)&vs[t >> 2][40 + ((t & 3) << 1)] = 0u;
    }

#pragma unroll
    for (int it = 0; it < 7; ++it) {
        const int idx = l + it * 64;
        if (idx < 400) {
            const int j = idx / 10, d4 = (idx % 10) << 2;
            const ushort4 vv = *(const ushort4*)(v + base + j * 40 + d4);
            vs[d4 + 0][j] = vv.x; vs[d4 + 1][j] = vv.y;
            vs[d4 + 2][j] = vv.z; vs[d4 + 3][j] = vv.w;
        }
    }

    f32x4 sacc[3][3];
#pragma unroll
    for (int mt = 0; mt < 3; ++mt)
#pragma unroll
        for (int jt = 0; jt < 3; ++jt) sacc[mt][jt] = zero4();

    {
        bf16x8 aq[3], bk0[3];
#pragma unroll
        for (int mt = 0; mt < 3; ++mt)
            aq[mt] = *(const bf16x8*)(q + base + (size_t)(mt * 16 + c) * 40 + g * 8);
#pragma unroll
        for (int jt = 0; jt < 3; ++jt)
            bk0[jt] = *(const bf16x8*)(k + base + (size_t)(jt * 16 + c) * 40 + g * 8);
#pragma unroll
        for (int mt = 0; mt < 3; ++mt)
#pragma unroll
            for (int jt = 0; jt < 3; ++jt)
                sacc[mt][jt] = __builtin_amdgcn_mfma_f32_16x16x32_bf16(
                    aq[mt], bk0[jt], sacc[mt][jt], 0, 0, 0);

        bf16x8 aq1[3], bk1[3];
#pragma unroll
        for (int mt = 0; mt < 3; ++mt)
            aq1[mt] = (g == 0)
                ? *(const bf16x8*)(q + base + (size_t)(mt * 16 + c) * 40 + 32)
                : zero8();
#pragma unroll
        for (int jt = 0; jt < 3; ++jt)
            bk1[jt] = (g == 0)
                ? *(const bf16x8*)(k + base + (size_t)(jt * 16 + c) * 40 + 32)
                : zero8();
#pragma unroll
        for (int mt = 0; mt < 3; ++mt)
#pragma unroll
            for (int jt = 0; jt < 3; ++jt)
                sacc[mt][jt] = __builtin_amdgcn_mfma_f32_16x16x32_bf16(
                    aq1[mt], bk1[jt], sacc[mt][jt], 0, 0, 0);
    }

    const bool val2 = (c < 8);
#pragma unroll
    for (int mt = 0; mt < 3; ++mt) {
#pragma unroll
        for (int r = 0; r < 4; ++r) {
            const float v0 = sacc[mt][0][r];
            const float v1 = sacc[mt][1][r];
            const float v2 = sacc[mt][2][r];
            float mx = fmaxf(fmaxf(v0, v1), val2 ? v2 : -1e30f);
#pragma unroll
            for (int off = 1; off < 16; off <<= 1)
                mx = fmaxf(mx, __shfl_xor(mx, off, 64));
            const float p0 = __expf((v0 - mx) * SCALE);
            const float p1 = __expf((v1 - mx) * SCALE);
            const float p2 = val2 ? __expf((v2 - mx) * SCALE) : 0.f;
            float sum = p0 + p1 + p2;
#pragma unroll
            for (int off = 1; off < 16; off <<= 1)
                sum += __shfl_xor(sum, off, 64);
            const float inv = 3.0f / sum;
            const int ri = mt * 16 + g * 4 + r;
            ps[ri][c]      = f2bf(p0 * inv);
            ps[ri][c + 16] = f2bf(p1 * inv);
            ps[ri][c + 32] = f2bf(p2 * inv);
        }
    }
    __syncthreads();

    f32x4 oacc[3][3];
#pragma unroll
    for (int mt = 0; mt < 3; ++mt)
#pragma unroll
        for (int nt = 0; nt < 3; ++nt) oacc[mt][nt] = zero4();

    {
        bf16x8 pa[3], vb_[3];
#pragma unroll
        for (int mt = 0; mt < 3; ++mt)
            pa[mt] = *(const bf16x8*)&ps[mt * 16 + c][g * 8];
#pragma unroll
        for (int nt = 0; nt < 3; ++nt)
            vb_[nt] = *(const bf16x8*)&vs[nt * 16 + c][g * 8];
#pragma unroll
        for (int mt = 0; mt < 3; ++mt)
#pragma unroll
            for (int nt = 0; nt < 3; ++nt)
                oacc[mt][nt] = __builtin_amdgcn_mfma_f32_16x16x32_bf16(
                    pa[mt], vb_[nt], oacc[mt][nt], 0, 0, 0);

        bf16x8 pa1[3], vb1[3];
#pragma unroll
        for (int mt = 0; mt < 3; ++mt)
            pa1[mt] = (g < 2) ? *(const bf16x8*)&ps[mt * 16 + c][32 + g * 8] : zero8();
#pragma unroll
        for (int nt = 0; nt < 3; ++nt)
            vb1[nt] = (g < 2) ? *(const bf16x8*)&vs[nt * 16 + c][32 + g * 8] : zero8();
#pragma unroll
        for (int mt = 0; mt < 3; ++mt)
#pragma unroll
            for (int nt = 0; nt < 3; ++nt)
                oacc[mt][nt] = __builtin_amdgcn_mfma_f32_16x16x32_bf16(
                    pa1[mt], vb1[nt], oacc[mt][nt], 0, 0, 0);
    }
    __syncthreads();

#pragma unroll
    for (int mt = 0; mt < 3; ++mt) {
        if (mt == 2 && g >= 2) continue;
#pragma unroll
        for (int r = 0; r < 4; ++r) {
            const int ri = mt * 16 + g * 4 + r;
#pragma unroll
            for (int nt = 0; nt < 3; ++nt) {
                if (nt == 2 && c >= 8) continue;
                ps[ri][nt * 16 + c] = f2bf(oacc[mt][nt][r]);
            }
        }
    }
    __syncthreads();

#pragma unroll
    for (int it = 0; it < 7; ++it) {
        const int idx = l + it * 64;
        if (idx < 400) {
            const int i = idx / 10, d4 = (idx % 10) << 2;
            *(ushort4*)(a + base + (size_t)idx * 4) = *(const ushort4*)&ps[i][d4];
        }
    }
}

// ---------------------------------------------------------------------------
// Proj v3: same low-register structure (M=128, m2 = bx%2 innermost), fp32 out.
// ---------------------------------------------------------------------------
__global__ __launch_bounds__(256, 4) void proj3(
    const u16* __restrict__ a, const u16* __restrict__ wpb,
    const float* __restrict__ bp, float* __restrict__ out)
{
    const int b    = blockIdx.z;
    const int m2   = blockIdx.x & 1;
    const int gx   = blockIdx.x >> 1;     // 0..249
    const int t    = threadIdx.x;
    const int lane = t & 63;
    const int wid  = t >> 6;
    const int row  = lane & 15;
    const int kg   = (lane >> 4) << 3;
    const int g4   = (lane >> 4) << 2;

    __shared__ u16 xs[64][264];

    const u16* ab = a + (size_t)b * NC * NSP;

    const int orow = m2 * 128 + wid * 32;
    bf16x8 af[8][2];
#pragma unroll
    for (int kc = 0; kc < 8; ++kc)
#pragma unroll
        for (int i = 0; i < 2; ++i)
            af[kc][i] = *(const bf16x8*)(wpb + (size_t)(orow + 16 * i + row) * NC
                                             + kc * 32 + kg);

    float* ob = out + (size_t)b * NC * NSP;

    for (int tt = 0; tt < 4; ++tt) {
        const int n0 = (gx * 4 + tt) * 64;

        __syncthreads();
        {
            const int p   = t >> 4;
            const int nn  = (t & 15) << 2;
            const int rot = (t >> 1) & 3;
#pragma unroll
            for (int it = 0; it < 8; ++it) {
                const int c = (it * 16 + p) * 2;
                const ushort4 ua = *(const ushort4*)(ab + (size_t)c * NSP + n0 + nn);
                const ushort4 ub = *(const ushort4*)(ab + (size_t)(c + 1) * NSP + n0 + nn);
                u32 pk[4] = { (u32)ua.x | ((u32)ub.x << 16), (u32)ua.y | ((u32)ub.y << 16),
                              (u32)ua.z | ((u32)ub.z << 16), (u32)ua.w | ((u32)ub.w << 16) };
#pragma unroll
                for (int kk = 0; kk < 4; ++kk) {
                    const int k2 = (kk + rot) & 3;
                    *(u32*)&xs[nn + k2][c] = pk[k2];
                }
            }
        }
        __syncthreads();

        f32x4 acc[2][4];
#pragma unroll
        for (int i = 0; i < 2; ++i)
#pragma unroll
            for (int j = 0; j < 4; ++j) acc[i][j] = zero4();

#pragma unroll
        for (int kc = 0; kc < 8; ++kc) {
            bf16x8 bfr[4];
#pragma unroll
            for (int j = 0; j < 4; ++j)
                bfr[j] = *(const bf16x8*)&xs[16 * j + row][kc * 32 + kg];
#pragma unroll
            for (int i = 0; i < 2; ++i)
#pragma unroll
                for (int j = 0; j < 4; ++j)
                    acc[i][j] = __builtin_amdgcn_mfma_f32_16x16x32_bf16(
                        af[kc][i], bfr[j], acc[i][j], 0, 0, 0);
        }

#pragma unroll
        for (int i = 0; i < 2; ++i) {
#pragma unroll
            for (int r = 0; r < 4; ++r) {
                const int o = orow + 16 * i + g4 + r;
                const float bb = bp[o];
#pragma unroll
                for (int j = 0; j < 4; ++j) {
                    const int n = n0 + 16 * j + row;
                    ob[(size_t)o * NSP + n] = acc[i][j][r] + bb;
                }
            }
        }
    }
}

extern "C" void kernel_launch(void* const* d_in, const int* in_sizes, int n_in,
                              void* d_out, int out_size, void* d_ws, size_t ws_size,
                              hipStream_t stream)
{
    const float* x  = (const float*)d_in[0];
    const float* wq = (const float*)d_in[1];
    const float* bq = (const float*)d_in[2];
    const float* wk = (const float*)d_in[3];
    const float* bk = (const float*)d_in[4];
    const float* wv = (const float*)d_in[5];
    const float* bv = (const float*)d_in[6];
    const float* wp = (const float*)d_in[7];
    const float* bp = (const float*)d_in[8];
    float* out = (float*)d_out;

    const size_t QE = (size_t)NB * NC * NSP;   // 32,768,000 elems
    u16* qb = (u16*)d_ws;
    u16* kb = qb + QE;
    u16* vb = kb + QE;
    u16* ab = vb + QE;                         // 262.1 MB total in d_ws

    u16* wqkv = (u16*)d_out;                   // scratch until proj overwrites
    u16* wpb  = qb;                            // qb dead after attn

    wcvt3<<<192, 256, 0, stream>>>(wq, wk, wv, wqkv);
    qkv3<<<dim3(1500, 1, NB), 256, 0, stream>>>(
        x, wqkv, bq, bk, bv, qb, kb, vb);
    attn_mfma<<<dim3(NB * NC * NHH), 64, 0, stream>>>(qb, kb, vb, ab);
    wcvt1<<<64, 256, 0, stream>>>(wp, wpb);
    proj3<<<dim3(500, 1, NB), 256, 0, stream>>>(ab, wpb, bp, out);
}

// Round 11
// 249.031 us; speedup vs baseline: 1.8209x; 1.8209x over previous
//
#include <hip/hip_runtime.h>

#define NB 2
#define NC 256
#define NHH 40
#define NSP 64000      // 40*40*40
#define PL 1600        // 40*40
#define SCALE 0.17677669529663687f  // 1/sqrt(32)

typedef unsigned short u16;
typedef unsigned int   u32;

typedef __attribute__((ext_vector_type(8))) short bf16x8;  // 8 bf16 = 4 VGPRs
typedef __attribute__((ext_vector_type(4))) float f32x4;

__device__ __forceinline__ float bf2f(u16 u) {
    union { u32 i; float f; } c; c.i = ((u32)u) << 16; return c.f;
}
__device__ __forceinline__ u16 f2bf(float f) {
    union { u32 i; float f; } c; c.f = f; u32 x = c.i;
    return (u16)((x + 0x7fffu + ((x >> 16) & 1u)) >> 16);
}
__device__ __forceinline__ u32 pack2(float a, float b) {
    return (u32)f2bf(a) | ((u32)f2bf(b) << 16);
}
__device__ __forceinline__ f32x4 zero4() {
    f32x4 z; z[0] = 0.f; z[1] = 0.f; z[2] = 0.f; z[3] = 0.f; return z;
}
__device__ __forceinline__ bf16x8 zero8() {
    bf16x8 z;
#pragma unroll
    for (int e = 0; e < 8; ++e) z[e] = 0;
    return z;
}

// ---------------------------------------------------------------------------
// Weight pre-conversion fp32 -> bf16 ([768][256] concat for qkv; [256][256] wp)
// ---------------------------------------------------------------------------
__global__ __launch_bounds__(256) void wcvt3(
    const float* __restrict__ wq, const float* __restrict__ wk,
    const float* __restrict__ wv, u16* __restrict__ dst)
{
    const int g   = blockIdx.x * 256 + threadIdx.x;
    const int mat = g >> 14;
    const int off = (g & 16383) << 2;
    const float* s = (mat == 0) ? wq : ((mat == 1) ? wk : wv);
    const float4 f = *(const float4*)(s + off);
    ushort4 p;
    p.x = f2bf(f.x); p.y = f2bf(f.y); p.z = f2bf(f.z); p.w = f2bf(f.w);
    *(ushort4*)(dst + (mat << 16) + off) = p;
}

__global__ __launch_bounds__(256) void wcvt1(
    const float* __restrict__ w, u16* __restrict__ dst)
{
    const int g   = blockIdx.x * 256 + threadIdx.x;
    const int off = g << 2;
    const float4 f = *(const float4*)(w + off);
    ushort4 p;
    p.x = f2bf(f.x); p.y = f2bf(f.y); p.z = f2bf(f.z); p.w = f2bf(f.w);
    *(ushort4*)(dst + off) = p;
}

// ---------------------------------------------------------------------------
// QKV v4: round-4 traffic-optimal structure (X staged ONCE per block, all 3
// mats computed from it; W streamed via double-buffered LDS) at 512 threads
// (8 waves, 32 o-rows each) -> 2 blocks/CU = 16 waves/CU (vs 8 in round 4).
// Per step: W-chunk prefetch to regs + 8 MFMA/wave + reg->LDS + 1 barrier.
// ---------------------------------------------------------------------------
__global__ __launch_bounds__(512, 4) void qkv4(
    const float* __restrict__ x, const u16* __restrict__ wb,  // [768][256] bf16
    const float* __restrict__ bq, const float* __restrict__ bk,
    const float* __restrict__ bv,
    u16* __restrict__ q, u16* __restrict__ k, u16* __restrict__ v)
{
    const int b    = blockIdx.z;
    const int n0   = blockIdx.x * 64;
    const int t    = threadIdx.x;          // 0..511
    const int lane = t & 63;
    const int wid  = t >> 6;               // 0..7
    const int o0w  = wid * 32;
    const int row  = lane & 15;
    const int kg   = (lane >> 4) << 3;     // 0,8,16,24
    const int g4   = (lane >> 4) << 2;     // 0,4,8,12

    __shared__ u16 xs[64][264];            // [n][c] transposed X tile (33.8 KB)
    __shared__ u16 wsm[2][256][40];        // [buf][o][kchunk 32 pad 40] (40 KB)

    const float* xb = x + (size_t)b * NC * NSP;

    // ---- stage X once: transpose to [n][c], fp32 -> bf16; rotated writes ----
    {
        const int p   = t >> 4;            // 0..31 c-pair group
        const int nn  = (t & 15) << 2;     // rows nn..nn+3
        const int rot = (t >> 1) & 3;
#pragma unroll
        for (int it = 0; it < 4; ++it) {
            const int c = (it * 32 + p) * 2;
            const float4 fa = *(const float4*)(xb + (size_t)c * NSP + n0 + nn);
            const float4 fb = *(const float4*)(xb + (size_t)(c + 1) * NSP + n0 + nn);
            u32 pk[4] = { pack2(fa.x, fb.x), pack2(fa.y, fb.y),
                          pack2(fa.z, fb.z), pack2(fa.w, fb.w) };
#pragma unroll
            for (int kk = 0; kk < 4; ++kk) {
                const int k2 = (kk + rot) & 3;
                *(u32*)&xs[nn + k2][c] = pk[k2];
            }
        }
    }

    // ---- stage W chunk for step 0 (mat 0, kc 0): thread pair per row ----
    const int wrow = t >> 1;               // 0..255
    const int wseg = (t & 1) << 4;         // 0 or 16
    {
        const u16* ws0 = wb + (size_t)wrow * NC + wseg;
        *(bf16x8*)&wsm[0][wrow][wseg]     = *(const bf16x8*)(ws0);
        *(bf16x8*)&wsm[0][wrow][wseg + 8] = *(const bf16x8*)(ws0 + 8);
    }
    __syncthreads();

    f32x4 acc[2][4];
#pragma unroll
    for (int i = 0; i < 2; ++i)
#pragma unroll
        for (int j = 0; j < 4; ++j) acc[i][j] = zero4();

    int cur = 0;
    for (int step = 0; step < 24; ++step) {
        const int m  = step >> 3;
        const int kc = step & 7;
        const bool pf = (step + 1 < 24);

        // prefetch next W chunk (32 B per thread)
        bf16x8 wreg[2];
        if (pf) {
            const int m2  = (step + 1) >> 3;
            const int kc2 = (step + 1) & 7;
            const u16* ws2 = wb + ((size_t)m2 << 16) + (size_t)wrow * NC
                                + kc2 * 32 + wseg;
            wreg[0] = *(const bf16x8*)(ws2);
            wreg[1] = *(const bf16x8*)(ws2 + 8);
        }

        // compute current chunk: 8 MFMA per wave
        bf16x8 af[2], bfr[4];
#pragma unroll
        for (int i = 0; i < 2; ++i)
            af[i] = *(const bf16x8*)&wsm[cur][o0w + 16 * i + row][kg];
#pragma unroll
        for (int j = 0; j < 4; ++j)
            bfr[j] = *(const bf16x8*)&xs[16 * j + row][kc * 32 + kg];
#pragma unroll
        for (int i = 0; i < 2; ++i)
#pragma unroll
            for (int j = 0; j < 4; ++j)
                acc[i][j] = __builtin_amdgcn_mfma_f32_16x16x32_bf16(
                    af[i], bfr[j], acc[i][j], 0, 0, 0);

        // write prefetched chunk into the other buffer
        if (pf) {
            *(bf16x8*)&wsm[cur ^ 1][wrow][wseg]     = wreg[0];
            *(bf16x8*)&wsm[cur ^ 1][wrow][wseg + 8] = wreg[1];
        }

        // epilogue per mat
        if (kc == 7) {
            u16* op = ((m == 0) ? q : ((m == 1) ? k : v)) + (size_t)b * NC * NSP;
            const float* bm = (m == 0) ? bq : ((m == 1) ? bk : bv);
#pragma unroll
            for (int i = 0; i < 2; ++i) {
#pragma unroll
                for (int r = 0; r < 4; ++r) {
                    const int o = o0w + 16 * i + g4 + r;
                    const float bb = bm[o];
#pragma unroll
                    for (int j = 0; j < 4; ++j) {
                        const int n = n0 + 16 * j + row;
                        op[(size_t)o * NSP + n] = f2bf(acc[i][j][r] + bb);
                    }
                }
            }
#pragma unroll
            for (int i = 0; i < 2; ++i)
#pragma unroll
                for (int j = 0; j < 4; ++j) acc[i][j] = zero4();
        }

        if (pf) {
            __syncthreads();
            cur ^= 1;
        }
    }
}

// ---------------------------------------------------------------------------
// Attention via MFMA (unchanged): 1 wave per (b,ch,h) slice.
// ---------------------------------------------------------------------------
__global__ __launch_bounds__(64, 4) void attn_mfma(
    const u16* __restrict__ q, const u16* __restrict__ k,
    const u16* __restrict__ v, u16* __restrict__ a)
{
    const int s = blockIdx.x;
    const size_t base = (size_t)s * PL;
    const int l = threadIdx.x & 63;
    const int g = l >> 4;
    const int c = l & 15;

    __shared__ u16 vs[48][56];
    __shared__ u16 ps[48][56];

#pragma unroll
    for (int it = 0; it < 3; ++it) {
        const int t = l + it * 64;
        *(u32*)&vs[t >> 2][40 + ((t & 3) << 1)] = 0u;
    }

#pragma unroll
    for (int it = 0; it < 7; ++it) {
        const int idx = l + it * 64;
        if (idx < 400) {
            const int j = idx / 10, d4 = (idx % 10) << 2;
            const ushort4 vv = *(const ushort4*)(v + base + j * 40 + d4);
            vs[d4 + 0][j] = vv.x; vs[d4 + 1][j] = vv.y;
            vs[d4 + 2][j] = vv.z; vs[d4 + 3][j] = vv.w;
        }
    }

    f32x4 sacc[3][3];
#pragma unroll
    for (int mt = 0; mt < 3; ++mt)
#pragma unroll
        for (int jt = 0; jt < 3; ++jt) sacc[mt][jt] = zero4();

    {
        bf16x8 aq[3], bk0[3];
#pragma unroll
        for (int mt = 0; mt < 3; ++mt)
            aq[mt] = *(const bf16x8*)(q + base + (size_t)(mt * 16 + c) * 40 + g * 8);
#pragma unroll
        for (int jt = 0; jt < 3; ++jt)
            bk0[jt] = *(const bf16x8*)(k + base + (size_t)(jt * 16 + c) * 40 + g * 8);
#pragma unroll
        for (int mt = 0; mt < 3; ++mt)
#pragma unroll
            for (int jt = 0; jt < 3; ++jt)
                sacc[mt][jt] = __builtin_amdgcn_mfma_f32_16x16x32_bf16(
                    aq[mt], bk0[jt], sacc[mt][jt], 0, 0, 0);

        bf16x8 aq1[3], bk1[3];
#pragma unroll
        for (int mt = 0; mt < 3; ++mt)
            aq1[mt] = (g == 0)
                ? *(const bf16x8*)(q + base + (size_t)(mt * 16 + c) * 40 + 32)
                : zero8();
#pragma unroll
        for (int jt = 0; jt < 3; ++jt)
            bk1[jt] = (g == 0)
                ? *(const bf16x8*)(k + base + (size_t)(jt * 16 + c) * 40 + 32)
                : zero8();
#pragma unroll
        for (int mt = 0; mt < 3; ++mt)
#pragma unroll
            for (int jt = 0; jt < 3; ++jt)
                sacc[mt][jt] = __builtin_amdgcn_mfma_f32_16x16x32_bf16(
                    aq1[mt], bk1[jt], sacc[mt][jt], 0, 0, 0);
    }

    const bool val2 = (c < 8);
#pragma unroll
    for (int mt = 0; mt < 3; ++mt) {
#pragma unroll
        for (int r = 0; r < 4; ++r) {
            const float v0 = sacc[mt][0][r];
            const float v1 = sacc[mt][1][r];
            const float v2 = sacc[mt][2][r];
            float mx = fmaxf(fmaxf(v0, v1), val2 ? v2 : -1e30f);
#pragma unroll
            for (int off = 1; off < 16; off <<= 1)
                mx = fmaxf(mx, __shfl_xor(mx, off, 64));
            const float p0 = __expf((v0 - mx) * SCALE);
            const float p1 = __expf((v1 - mx) * SCALE);
            const float p2 = val2 ? __expf((v2 - mx) * SCALE) : 0.f;
            float sum = p0 + p1 + p2;
#pragma unroll
            for (int off = 1; off < 16; off <<= 1)
                sum += __shfl_xor(sum, off, 64);
            const float inv = 3.0f / sum;
            const int ri = mt * 16 + g * 4 + r;
            ps[ri][c]      = f2bf(p0 * inv);
            ps[ri][c + 16] = f2bf(p1 * inv);
            ps[ri][c + 32] = f2bf(p2 * inv);
        }
    }
    __syncthreads();

    f32x4 oacc[3][3];
#pragma unroll
    for (int mt = 0; mt < 3; ++mt)
#pragma unroll
        for (int nt = 0; nt < 3; ++nt) oacc[mt][nt] = zero4();

    {
        bf16x8 pa[3], vb_[3];
#pragma unroll
        for (int mt = 0; mt < 3; ++mt)
            pa[mt] = *(const bf16x8*)&ps[mt * 16 + c][g * 8];
#pragma unroll
        for (int nt = 0; nt < 3; ++nt)
            vb_[nt] = *(const bf16x8*)&vs[nt * 16 + c][g * 8];
#pragma unroll
        for (int mt = 0; mt < 3; ++mt)
#pragma unroll
            for (int nt = 0; nt < 3; ++nt)
                oacc[mt][nt] = __builtin_amdgcn_mfma_f32_16x16x32_bf16(
                    pa[mt], vb_[nt], oacc[mt][nt], 0, 0, 0);

        bf16x8 pa1[3], vb1[3];
#pragma unroll
        for (int mt = 0; mt < 3; ++mt)
            pa1[mt] = (g < 2) ? *(const bf16x8*)&ps[mt * 16 + c][32 + g * 8] : zero8();
#pragma unroll
        for (int nt = 0; nt < 3; ++nt)
            vb1[nt] = (g < 2) ? *(const bf16x8*)&vs[nt * 16 + c][32 + g * 8] : zero8();
#pragma unroll
        for (int mt = 0; mt < 3; ++mt)
#pragma unroll
            for (int nt = 0; nt < 3; ++nt)
                oacc[mt][nt] = __builtin_amdgcn_mfma_f32_16x16x32_bf16(
                    pa1[mt], vb1[nt], oacc[mt][nt], 0, 0, 0);
    }
    __syncthreads();

#pragma unroll
    for (int mt = 0; mt < 3; ++mt) {
        if (mt == 2 && g >= 2) continue;
#pragma unroll
        for (int r = 0; r < 4; ++r) {
            const int ri = mt * 16 + g * 4 + r;
#pragma unroll
            for (int nt = 0; nt < 3; ++nt) {
                if (nt == 2 && c >= 8) continue;
                ps[ri][nt * 16 + c] = f2bf(oacc[mt][nt][r]);
            }
        }
    }
    __syncthreads();

#pragma unroll
    for (int it = 0; it < 7; ++it) {
        const int idx = l + it * 64;
        if (idx < 400) {
            const int i = idx / 10, d4 = (idx % 10) << 2;
            *(ushort4*)(a + base + (size_t)idx * 4) = *(const ushort4*)&ps[i][d4];
        }
    }
}

// ---------------------------------------------------------------------------
// Proj v4: same 512-thread structure, single mat (8 steps), fp32 out.
// ---------------------------------------------------------------------------
__global__ __launch_bounds__(512, 4) void proj4(
    const u16* __restrict__ a, const u16* __restrict__ wpb,
    const float* __restrict__ bp, float* __restrict__ out)
{
    const int b    = blockIdx.z;
    const int n0   = blockIdx.x * 64;
    const int t    = threadIdx.x;
    const int lane = t & 63;
    const int wid  = t >> 6;
    const int o0w  = wid * 32;
    const int row  = lane & 15;
    const int kg   = (lane >> 4) << 3;
    const int g4   = (lane >> 4) << 2;

    __shared__ u16 xs[64][264];
    __shared__ u16 wsm[2][256][40];

    const u16* ab = a + (size_t)b * NC * NSP;

    {
        const int p   = t >> 4;            // 0..31
        const int nn  = (t & 15) << 2;
        const int rot = (t >> 1) & 3;
#pragma unroll
        for (int it = 0; it < 4; ++it) {
            const int c = (it * 32 + p) * 2;
            const ushort4 ua = *(const ushort4*)(ab + (size_t)c * NSP + n0 + nn);
            const ushort4 ub = *(const ushort4*)(ab + (size_t)(c + 1) * NSP + n0 + nn);
            u32 pk[4] = { (u32)ua.x | ((u32)ub.x << 16), (u32)ua.y | ((u32)ub.y << 16),
                          (u32)ua.z | ((u32)ub.z << 16), (u32)ua.w | ((u32)ub.w << 16) };
#pragma unroll
            for (int kk = 0; kk < 4; ++kk) {
                const int k2 = (kk + rot) & 3;
                *(u32*)&xs[nn + k2][c] = pk[k2];
            }
        }
    }

    const int wrow = t >> 1;
    const int wseg = (t & 1) << 4;
    {
        const u16* ws0 = wpb + (size_t)wrow * NC + wseg;
        *(bf16x8*)&wsm[0][wrow][wseg]     = *(const bf16x8*)(ws0);
        *(bf16x8*)&wsm[0][wrow][wseg + 8] = *(const bf16x8*)(ws0 + 8);
    }
    __syncthreads();

    f32x4 acc[2][4];
#pragma unroll
    for (int i = 0; i < 2; ++i)
#pragma unroll
        for (int j = 0; j < 4; ++j) acc[i][j] = zero4();

    int cur = 0;
    for (int step = 0; step < 8; ++step) {
        const bool pf = (step + 1 < 8);
        bf16x8 wreg[2];
        if (pf) {
            const u16* ws2 = wpb + (size_t)wrow * NC + (step + 1) * 32 + wseg;
            wreg[0] = *(const bf16x8*)(ws2);
            wreg[1] = *(const bf16x8*)(ws2 + 8);
        }

        bf16x8 af[2], bfr[4];
#pragma unroll
        for (int i = 0; i < 2; ++i)
            af[i] = *(const bf16x8*)&wsm[cur][o0w + 16 * i + row][kg];
#pragma unroll
        for (int j = 0; j < 4; ++j)
            bfr[j] = *(const bf16x8*)&xs[16 * j + row][step * 32 + kg];
#pragma unroll
        for (int i = 0; i < 2; ++i)
#pragma unroll
            for (int j = 0; j < 4; ++j)
                acc[i][j] = __builtin_amdgcn_mfma_f32_16x16x32_bf16(
                    af[i], bfr[j], acc[i][j], 0, 0, 0);

        if (pf) {
            *(bf16x8*)&wsm[cur ^ 1][wrow][wseg]     = wreg[0];
            *(bf16x8*)&wsm[cur ^ 1][wrow][wseg + 8] = wreg[1];
            __syncthreads();
            cur ^= 1;
        }
    }

    float* ob = out + (size_t)b * NC * NSP;
#pragma unroll
    for (int i = 0; i < 2; ++i) {
#pragma unroll
        for (int r = 0; r < 4; ++r) {
            const int o = o0w + 16 * i + g4 + r;
            const float bb = bp[o];
#pragma unroll
            for (int j = 0; j < 4; ++j) {
                const int n = n0 + 16 * j + row;
                ob[(size_t)o * NSP + n] = acc[i][j][r] + bb;
            }
        }
    }
}

extern "C" void kernel_launch(void* const* d_in, const int* in_sizes, int n_in,
                              void* d_out, int out_size, void* d_ws, size_t ws_size,
                              hipStream_t stream)
{
    const float* x  = (const float*)d_in[0];
    const float* wq = (const float*)d_in[1];
    const float* bq = (const float*)d_in[2];
    const float* wk = (const float*)d_in[3];
    const float* bk = (const float*)d_in[4];
    const float* wv = (const float*)d_in[5];
    const float* bv = (const float*)d_in[6];
    const float* wp = (const float*)d_in[7];
    const float* bp = (const float*)d_in[8];
    float* out = (float*)d_out;

    const size_t QE = (size_t)NB * NC * NSP;   // 32,768,000 elems
    u16* qb = (u16*)d_ws;
    u16* kb = qb + QE;
    u16* vb = kb + QE;
    u16* ab = vb + QE;                         // 262.1 MB total in d_ws

    u16* wqkv = (u16*)d_out;                   // scratch until proj overwrites
    u16* wpb  = qb;                            // qb dead after attn

    wcvt3<<<192, 256, 0, stream>>>(wq, wk, wv, wqkv);
    qkv4<<<dim3(NSP / 64, 1, NB), 512, 0, stream>>>(
        x, wqkv, bq, bk, bv, qb, kb, vb);
    attn_mfma<<<dim3(NB * NC * NHH), 64, 0, stream>>>(qb, kb, vb, ab);
    wcvt1<<<64, 256, 0, stream>>>(wp, wpb);
    proj4<<<dim3(NSP / 64, 1, NB), 512, 0, stream>>>(ab, wpb, bp, out);
}

// Round 12
// 234.748 us; speedup vs baseline: 1.9317x; 1.0608x over previous
//
#include <hip/hip_runtime.h>

#define NB 2
#define NC 256
#define NHH 40
#define NSP 64000      // 40*40*40
#define PL 1600        // 40*40
#define SCALE 0.17677669529663687f  // 1/sqrt(32)

typedef unsigned short u16;
typedef unsigned int   u32;

typedef __attribute__((ext_vector_type(8))) short bf16x8;  // 8 bf16 = 4 VGPRs
typedef __attribute__((ext_vector_type(4))) float f32x4;

__device__ __forceinline__ float bf2f(u16 u) {
    union { u32 i; float f; } c; c.i = ((u32)u) << 16; return c.f;
}
__device__ __forceinline__ u16 f2bf(float f) {
    union { u32 i; float f; } c; c.f = f; u32 x = c.i;
    return (u16)((x + 0x7fffu + ((x >> 16) & 1u)) >> 16);
}
__device__ __forceinline__ u32 pack2(float a, float b) {
    return (u32)f2bf(a) | ((u32)f2bf(b) << 16);
}
__device__ __forceinline__ f32x4 zero4() {
    f32x4 z; z[0] = 0.f; z[1] = 0.f; z[2] = 0.f; z[3] = 0.f; return z;
}
__device__ __forceinline__ bf16x8 zero8() {
    bf16x8 z;
#pragma unroll
    for (int e = 0; e < 8; ++e) z[e] = 0;
    return z;
}

// ---------------------------------------------------------------------------
// Weight pre-layout: fp32 [o][c] -> bf16 FRAGMENT order [step][wid][i][lane][8]
// matching qkv5's per-wave MFMA A-operand reads exactly.
//   gid = step*1024 + wid*128 + i*64 + lane ; dst offset = gid*8
//   row = wid*32 + i*16 + (lane&15) ; col = (step&7)*32 + (lane>>4)*8
// qkv: 24 steps (m = step>>3 selects wq/wk/wv). proj: 8 steps, single mat.
// ---------------------------------------------------------------------------
__global__ __launch_bounds__(256) void wfrag3(
    const float* __restrict__ wq, const float* __restrict__ wk,
    const float* __restrict__ wv, u16* __restrict__ dst)
{
    const int gid  = blockIdx.x * 256 + threadIdx.x;   // 0..24575
    const int lane = gid & 63;
    const int i    = (gid >> 6) & 1;
    const int wid  = (gid >> 7) & 7;
    const int step = gid >> 10;                        // 0..23
    const int m    = step >> 3;
    const int kc   = step & 7;
    const int row  = wid * 32 + i * 16 + (lane & 15);
    const int col  = kc * 32 + ((lane >> 4) << 3);
    const float* s = ((m == 0) ? wq : ((m == 1) ? wk : wv)) + (size_t)row * NC + col;
    const float4 a = *(const float4*)(s);
    const float4 b = *(const float4*)(s + 4);
    ushort4 p0, p1;
    p0.x = f2bf(a.x); p0.y = f2bf(a.y); p0.z = f2bf(a.z); p0.w = f2bf(a.w);
    p1.x = f2bf(b.x); p1.y = f2bf(b.y); p1.z = f2bf(b.z); p1.w = f2bf(b.w);
    u16* d = dst + (size_t)gid * 8;
    *(ushort4*)(d)     = p0;
    *(ushort4*)(d + 4) = p1;
}

__global__ __launch_bounds__(256) void wfrag1(
    const float* __restrict__ w, u16* __restrict__ dst)
{
    const int gid  = blockIdx.x * 256 + threadIdx.x;   // 0..8191
    const int lane = gid & 63;
    const int i    = (gid >> 6) & 1;
    const int wid  = (gid >> 7) & 7;
    const int step = (gid >> 10) & 7;
    const int row  = wid * 32 + i * 16 + (lane & 15);
    const int col  = step * 32 + ((lane >> 4) << 3);
    const float* s = w + (size_t)row * NC + col;
    const float4 a = *(const float4*)(s);
    const float4 b = *(const float4*)(s + 4);
    ushort4 p0, p1;
    p0.x = f2bf(a.x); p0.y = f2bf(a.y); p0.z = f2bf(a.z); p0.w = f2bf(a.w);
    p1.x = f2bf(b.x); p1.y = f2bf(b.y); p1.z = f2bf(b.z); p1.w = f2bf(b.w);
    u16* d = dst + (size_t)gid * 8;
    *(ushort4*)(d)     = p0;
    *(ushort4*)(d + 4) = p1;
}

// ---------------------------------------------------------------------------
// QKV v5: barrier-free K-loop. X staged ONCE (transposed, 33.8 KB LDS);
// W A-fragments streamed from the pre-layouted wfrag buffer (contiguous
// 2 KB/wave/step, L2-resident), software-pipelined one step ahead.
// 512 thr (8 waves x 32 o-rows), all 3 mats per block, 16 waves/CU.
// ---------------------------------------------------------------------------
__global__ __launch_bounds__(512, 4) void qkv5(
    const float* __restrict__ x, const u16* __restrict__ wf,
    const float* __restrict__ bq, const float* __restrict__ bk,
    const float* __restrict__ bv,
    u16* __restrict__ q, u16* __restrict__ k, u16* __restrict__ v)
{
    const int b    = blockIdx.z;
    const int n0   = blockIdx.x * 64;
    const int t    = threadIdx.x;          // 0..511
    const int lane = t & 63;
    const int wid  = t >> 6;               // 0..7
    const int o0w  = wid * 32;
    const int row  = lane & 15;
    const int kg   = (lane >> 4) << 3;     // 0,8,16,24
    const int g4   = (lane >> 4) << 2;     // 0,4,8,12

    __shared__ u16 xs[64][264];            // [n][c] transposed X tile

    const float* xb = x + (size_t)b * NC * NSP;

    // ---- stage X once: transpose to [n][c], fp32 -> bf16; rotated writes ----
    {
        const int p   = t >> 4;            // 0..31 c-pair group
        const int nn  = (t & 15) << 2;     // rows nn..nn+3
        const int rot = (t >> 1) & 3;
#pragma unroll
        for (int it = 0; it < 4; ++it) {
            const int c = (it * 32 + p) * 2;
            const float4 fa = *(const float4*)(xb + (size_t)c * NSP + n0 + nn);
            const float4 fb = *(const float4*)(xb + (size_t)(c + 1) * NSP + n0 + nn);
            u32 pk[4] = { pack2(fa.x, fb.x), pack2(fa.y, fb.y),
                          pack2(fa.z, fb.z), pack2(fa.w, fb.w) };
#pragma unroll
            for (int kk = 0; kk < 4; ++kk) {
                const int k2 = (kk + rot) & 3;
                *(u32*)&xs[nn + k2][c] = pk[k2];
            }
        }
    }
    __syncthreads();   // the only barrier

    // per-wave fragment stream base: chunk stride 512 u16 per (step*16+wid*2+i)
    const u16* wfb = wf + (size_t)(wid * 2) * 512 + (size_t)lane * 8;

    f32x4 acc[2][4];
#pragma unroll
    for (int i = 0; i < 2; ++i)
#pragma unroll
        for (int j = 0; j < 4; ++j) acc[i][j] = zero4();

    // software pipeline: preload step 0
    bf16x8 afc[2], afn[2];
    afc[0] = *(const bf16x8*)(wfb);
    afc[1] = *(const bf16x8*)(wfb + 512);

    for (int step = 0; step < 24; ++step) {
        const int m  = step >> 3;
        const int kc = step & 7;
        const bool pf = (step + 1 < 24);

        if (pf) {
            const u16* wn = wfb + (size_t)(step + 1) * 8192;
            afn[0] = *(const bf16x8*)(wn);
            afn[1] = *(const bf16x8*)(wn + 512);
        }

        bf16x8 bfr[4];
#pragma unroll
        for (int j = 0; j < 4; ++j)
            bfr[j] = *(const bf16x8*)&xs[16 * j + row][kc * 32 + kg];
#pragma unroll
        for (int i = 0; i < 2; ++i)
#pragma unroll
            for (int j = 0; j < 4; ++j)
                acc[i][j] = __builtin_amdgcn_mfma_f32_16x16x32_bf16(
                    afc[i], bfr[j], acc[i][j], 0, 0, 0);

        if (kc == 7) {
            u16* op = ((m == 0) ? q : ((m == 1) ? k : v)) + (size_t)b * NC * NSP;
            const float* bm = (m == 0) ? bq : ((m == 1) ? bk : bv);
#pragma unroll
            for (int i = 0; i < 2; ++i) {
#pragma unroll
                for (int r = 0; r < 4; ++r) {
                    const int o = o0w + 16 * i + g4 + r;
                    const float bb = bm[o];
#pragma unroll
                    for (int j = 0; j < 4; ++j) {
                        const int n = n0 + 16 * j + row;
                        op[(size_t)o * NSP + n] = f2bf(acc[i][j][r] + bb);
                    }
                }
            }
#pragma unroll
            for (int i = 0; i < 2; ++i)
#pragma unroll
                for (int j = 0; j < 4; ++j) acc[i][j] = zero4();
        }

        afc[0] = afn[0];
        afc[1] = afn[1];
    }
}

// ---------------------------------------------------------------------------
// Attention via MFMA (unchanged): 1 wave per (b,ch,h) slice.
// ---------------------------------------------------------------------------
__global__ __launch_bounds__(64, 4) void attn_mfma(
    const u16* __restrict__ q, const u16* __restrict__ k,
    const u16* __restrict__ v, u16* __restrict__ a)
{
    const int s = blockIdx.x;
    const size_t base = (size_t)s * PL;
    const int l = threadIdx.x & 63;
    const int g = l >> 4;
    const int c = l & 15;

    __shared__ u16 vs[48][56];
    __shared__ u16 ps[48][56];

#pragma unroll
    for (int it = 0; it < 3; ++it) {
        const int t = l + it * 64;
        *(u32*)&vs[t >> 2][40 + ((t & 3) << 1)] = 0u;
    }

#pragma unroll
    for (int it = 0; it < 7; ++it) {
        const int idx = l + it * 64;
        if (idx < 400) {
            const int j = idx / 10, d4 = (idx % 10) << 2;
            const ushort4 vv = *(const ushort4*)(v + base + j * 40 + d4);
            vs[d4 + 0][j] = vv.x; vs[d4 + 1][j] = vv.y;
            vs[d4 + 2][j] = vv.z; vs[d4 + 3][j] = vv.w;
        }
    }

    f32x4 sacc[3][3];
#pragma unroll
    for (int mt = 0; mt < 3; ++mt)
#pragma unroll
        for (int jt = 0; jt < 3; ++jt) sacc[mt][jt] = zero4();

    {
        bf16x8 aq[3], bk0[3];
#pragma unroll
        for (int mt = 0; mt < 3; ++mt)
            aq[mt] = *(const bf16x8*)(q + base + (size_t)(mt * 16 + c) * 40 + g * 8);
#pragma unroll
        for (int jt = 0; jt < 3; ++jt)
            bk0[jt] = *(const bf16x8*)(k + base + (size_t)(jt * 16 + c) * 40 + g * 8);
#pragma unroll
        for (int mt = 0; mt < 3; ++mt)
#pragma unroll
            for (int jt = 0; jt < 3; ++jt)
                sacc[mt][jt] = __builtin_amdgcn_mfma_f32_16x16x32_bf16(
                    aq[mt], bk0[jt], sacc[mt][jt], 0, 0, 0);

        bf16x8 aq1[3], bk1[3];
#pragma unroll
        for (int mt = 0; mt < 3; ++mt)
            aq1[mt] = (g == 0)
                ? *(const bf16x8*)(q + base + (size_t)(mt * 16 + c) * 40 + 32)
                : zero8();
#pragma unroll
        for (int jt = 0; jt < 3; ++jt)
            bk1[jt] = (g == 0)
                ? *(const bf16x8*)(k + base + (size_t)(jt * 16 + c) * 40 + 32)
                : zero8();
#pragma unroll
        for (int mt = 0; mt < 3; ++mt)
#pragma unroll
            for (int jt = 0; jt < 3; ++jt)
                sacc[mt][jt] = __builtin_amdgcn_mfma_f32_16x16x32_bf16(
                    aq1[mt], bk1[jt], sacc[mt][jt], 0, 0, 0);
    }

    const bool val2 = (c < 8);
#pragma unroll
    for (int mt = 0; mt < 3; ++mt) {
#pragma unroll
        for (int r = 0; r < 4; ++r) {
            const float v0 = sacc[mt][0][r];
            const float v1 = sacc[mt][1][r];
            const float v2 = sacc[mt][2][r];
            float mx = fmaxf(fmaxf(v0, v1), val2 ? v2 : -1e30f);
#pragma unroll
            for (int off = 1; off < 16; off <<= 1)
                mx = fmaxf(mx, __shfl_xor(mx, off, 64));
            const float p0 = __expf((v0 - mx) * SCALE);
            const float p1 = __expf((v1 - mx) * SCALE);
            const float p2 = val2 ? __expf((v2 - mx) * SCALE) : 0.f;
            float sum = p0 + p1 + p2;
#pragma unroll
            for (int off = 1; off < 16; off <<= 1)
                sum += __shfl_xor(sum, off, 64);
            const float inv = 3.0f / sum;
            const int ri = mt * 16 + g * 4 + r;
            ps[ri][c]      = f2bf(p0 * inv);
            ps[ri][c + 16] = f2bf(p1 * inv);
            ps[ri][c + 32] = f2bf(p2 * inv);
        }
    }
    __syncthreads();

    f32x4 oacc[3][3];
#pragma unroll
    for (int mt = 0; mt < 3; ++mt)
#pragma unroll
        for (int nt = 0; nt < 3; ++nt) oacc[mt][nt] = zero4();

    {
        bf16x8 pa[3], vb_[3];
#pragma unroll
        for (int mt = 0; mt < 3; ++mt)
            pa[mt] = *(const bf16x8*)&ps[mt * 16 + c][g * 8];
#pragma unroll
        for (int nt = 0; nt < 3; ++nt)
            vb_[nt] = *(const bf16x8*)&vs[nt * 16 + c][g * 8];
#pragma unroll
        for (int mt = 0; mt < 3; ++mt)
#pragma unroll
            for (int nt = 0; nt < 3; ++nt)
                oacc[mt][nt] = __builtin_amdgcn_mfma_f32_16x16x32_bf16(
                    pa[mt], vb_[nt], oacc[mt][nt], 0, 0, 0);

        bf16x8 pa1[3], vb1[3];
#pragma unroll
        for (int mt = 0; mt < 3; ++mt)
            pa1[mt] = (g < 2) ? *(const bf16x8*)&ps[mt * 16 + c][32 + g * 8] : zero8();
#pragma unroll
        for (int nt = 0; nt < 3; ++nt)
            vb1[nt] = (g < 2) ? *(const bf16x8*)&vs[nt * 16 + c][32 + g * 8] : zero8();
#pragma unroll
        for (int mt = 0; mt < 3; ++mt)
#pragma unroll
            for (int nt = 0; nt < 3; ++nt)
                oacc[mt][nt] = __builtin_amdgcn_mfma_f32_16x16x32_bf16(
                    pa1[mt], vb1[nt], oacc[mt][nt], 0, 0, 0);
    }
    __syncthreads();

#pragma unroll
    for (int mt = 0; mt < 3; ++mt) {
        if (mt == 2 && g >= 2) continue;
#pragma unroll
        for (int r = 0; r < 4; ++r) {
            const int ri = mt * 16 + g * 4 + r;
#pragma unroll
            for (int nt = 0; nt < 3; ++nt) {
                if (nt == 2 && c >= 8) continue;
                ps[ri][nt * 16 + c] = f2bf(oacc[mt][nt][r]);
            }
        }
    }
    __syncthreads();

#pragma unroll
    for (int it = 0; it < 7; ++it) {
        const int idx = l + it * 64;
        if (idx < 400) {
            const int i = idx / 10, d4 = (idx % 10) << 2;
            *(ushort4*)(a + base + (size_t)idx * 4) = *(const ushort4*)&ps[i][d4];
        }
    }
}

// ---------------------------------------------------------------------------
// Proj v5: same barrier-free structure, 8 steps, fp32 out.
// ---------------------------------------------------------------------------
__global__ __launch_bounds__(512, 4) void proj5(
    const u16* __restrict__ a, const u16* __restrict__ wf,
    const float* __restrict__ bp, float* __restrict__ out)
{
    const int b    = blockIdx.z;
    const int n0   = blockIdx.x * 64;
    const int t    = threadIdx.x;
    const int lane = t & 63;
    const int wid  = t >> 6;
    const int o0w  = wid * 32;
    const int row  = lane & 15;
    const int kg   = (lane >> 4) << 3;
    const int g4   = (lane >> 4) << 2;

    __shared__ u16 xs[64][264];

    const u16* ab = a + (size_t)b * NC * NSP;

    {
        const int p   = t >> 4;
        const int nn  = (t & 15) << 2;
        const int rot = (t >> 1) & 3;
#pragma unroll
        for (int it = 0; it < 4; ++it) {
            const int c = (it * 32 + p) * 2;
            const ushort4 ua = *(const ushort4*)(ab + (size_t)c * NSP + n0 + nn);
            const ushort4 ub = *(const ushort4*)(ab + (size_t)(c + 1) * NSP + n0 + nn);
            u32 pk[4] = { (u32)ua.x | ((u32)ub.x << 16), (u32)ua.y | ((u32)ub.y << 16),
                          (u32)ua.z | ((u32)ub.z << 16), (u32)ua.w | ((u32)ub.w << 16) };
#pragma unroll
            for (int kk = 0; kk < 4; ++kk) {
                const int k2 = (kk + rot) & 3;
                *(u32*)&xs[nn + k2][c] = pk[k2];
            }
        }
    }
    __syncthreads();

    const u16* wfb = wf + (size_t)(wid * 2) * 512 + (size_t)lane * 8;

    f32x4 acc[2][4];
#pragma unroll
    for (int i = 0; i < 2; ++i)
#pragma unroll
        for (int j = 0; j < 4; ++j) acc[i][j] = zero4();

    bf16x8 afc[2], afn[2];
    afc[0] = *(const bf16x8*)(wfb);
    afc[1] = *(const bf16x8*)(wfb + 512);

#pragma unroll
    for (int step = 0; step < 8; ++step) {
        const bool pf = (step + 1 < 8);
        if (pf) {
            const u16* wn = wfb + (size_t)(step + 1) * 8192;
            afn[0] = *(const bf16x8*)(wn);
            afn[1] = *(const bf16x8*)(wn + 512);
        }

        bf16x8 bfr[4];
#pragma unroll
        for (int j = 0; j < 4; ++j)
            bfr[j] = *(const bf16x8*)&xs[16 * j + row][step * 32 + kg];
#pragma unroll
        for (int i = 0; i < 2; ++i)
#pragma unroll
            for (int j = 0; j < 4; ++j)
                acc[i][j] = __builtin_amdgcn_mfma_f32_16x16x32_bf16(
                    afc[i], bfr[j], acc[i][j], 0, 0, 0);

        afc[0] = afn[0];
        afc[1] = afn[1];
    }

    float* ob = out + (size_t)b * NC * NSP;
#pragma unroll
    for (int i = 0; i < 2; ++i) {
#pragma unroll
        for (int r = 0; r < 4; ++r) {
            const int o = o0w + 16 * i + g4 + r;
            const float bb = bp[o];
#pragma unroll
            for (int j = 0; j < 4; ++j) {
                const int n = n0 + 16 * j + row;
                ob[(size_t)o * NSP + n] = acc[i][j][r] + bb;
            }
        }
    }
}

extern "C" void kernel_launch(void* const* d_in, const int* in_sizes, int n_in,
                              void* d_out, int out_size, void* d_ws, size_t ws_size,
                              hipStream_t stream)
{
    const float* x  = (const float*)d_in[0];
    const float* wq = (const float*)d_in[1];
    const float* bq = (const float*)d_in[2];
    const float* wk = (const float*)d_in[3];
    const float* bk = (const float*)d_in[4];
    const float* wv = (const float*)d_in[5];
    const float* bv = (const float*)d_in[6];
    const float* wp = (const float*)d_in[7];
    const float* bp = (const float*)d_in[8];
    float* out = (float*)d_out;

    const size_t QE = (size_t)NB * NC * NSP;   // 32,768,000 elems
    u16* qb = (u16*)d_ws;
    u16* kb = qb + QE;
    u16* vb = kb + QE;
    u16* ab = vb + QE;                         // 262.1 MB total in d_ws

    u16* wqf = (u16*)d_out;                    // 384 KB frag layout (scratch)
    u16* wpf = qb;                             // qb dead after attn

    wfrag3<<<96, 256, 0, stream>>>(wq, wk, wv, wqf);
    qkv5<<<dim3(NSP / 64, 1, NB), 512, 0, stream>>>(
        x, wqf, bq, bk, bv, qb, kb, vb);
    attn_mfma<<<dim3(NB * NC * NHH), 64, 0, stream>>>(qb, kb, vb, ab);
    wfrag1<<<32, 256, 0, stream>>>(wp, wpf);
    proj5<<<dim3(NSP / 64, 1, NB), 512, 0, stream>>>(ab, wpf, bp, out);
}